// Round 2
// 129.621 us; speedup vs baseline: 1.0832x; 1.0832x over previous
//
#include <hip/hip_runtime.h>
#include <cstdint>

// ---------------------------------------------------------------------------
// COMPILE-TIME op list: constexpr replica of numpy's RNG stream.
// op = (kind<<4) | (w0<<2) | w1
// kinds: 0 RX, 1 RY, 2 RZ, 3 CRX(ctrl=w0,tgt=w1), 4 H, 5 SX, 6 CNOT(ctrl=w0,tgt=w1)
// ---------------------------------------------------------------------------
namespace crng {

typedef unsigned __int128 u128;

struct PCG {
    u128 state, inc;
    bool has32;
    uint32_t buf32;
};

constexpr u128 PCG_MULT = (((u128)2549297995355413924ULL) << 64) | (u128)4865540595714422341ULL;

constexpr uint64_t pcg_next64(PCG& g) {
    g.state = g.state * PCG_MULT + g.inc;
    uint64_t hi = (uint64_t)(g.state >> 64), lo = (uint64_t)g.state;
    unsigned rot = (unsigned)(g.state >> 122) & 63u;
    uint64_t v = hi ^ lo;
    return (v >> rot) | (v << ((64u - rot) & 63u));
}

constexpr uint32_t pcg_next32(PCG& g) {
    if (g.has32) { g.has32 = false; return g.buf32; }
    uint64_t n = pcg_next64(g);
    g.has32 = true;
    g.buf32 = (uint32_t)(n >> 32);
    return (uint32_t)n;
}

constexpr uint32_t hashmix(uint32_t& hc, uint32_t v) {
    v ^= hc; hc *= 0x931e8875u; v *= hc; v ^= v >> 16; return v;
}
constexpr uint32_t mixf(uint32_t x, uint32_t y) {
    uint32_t r = 0xca01f9ddu * x - 0x4973f715u * y;
    r ^= r >> 16;
    return r;
}

constexpr PCG seed_pcg(uint32_t entropy) {
    uint32_t pool[4] = {0, 0, 0, 0};
    uint32_t hc = 0x43b0d7e5u;
    pool[0] = hashmix(hc, entropy);
    for (int i = 1; i < 4; ++i) pool[i] = hashmix(hc, 0u);
    for (int s = 0; s < 4; ++s)
        for (int d = 0; d < 4; ++d)
            if (s != d) pool[d] = mixf(pool[d], hashmix(hc, pool[s]));

    uint32_t hb = 0x8b51f9ddu;
    uint32_t w[8] = {0, 0, 0, 0, 0, 0, 0, 0};
    for (int i = 0; i < 8; ++i) {
        uint32_t dv = pool[i & 3];
        dv ^= hb; hb *= 0x58f38dedu; dv *= hb; dv ^= dv >> 16;
        w[i] = dv;
    }
    uint64_t w64[4] = {0, 0, 0, 0};
    for (int i = 0; i < 4; ++i)
        w64[i] = (uint64_t)w[2 * i] | ((uint64_t)w[2 * i + 1] << 32);

    u128 initstate = (((u128)w64[0]) << 64) | (u128)w64[1];
    u128 initseq   = (((u128)w64[2]) << 64) | (u128)w64[3];
    PCG g = {};
    g.state = 0;
    g.inc = (initseq << 1) | (u128)1;
    g.state = g.state * PCG_MULT + g.inc;
    g.state += initstate;
    g.state = g.state * PCG_MULT + g.inc;
    g.has32 = false;
    g.buf32 = 0;
    return g;
}

constexpr uint32_t lemire32(PCG& g, uint32_t rng) {
    uint64_t rng_excl = (uint64_t)rng + 1;
    uint64_t m = (uint64_t)pcg_next32(g) * rng_excl;
    uint32_t leftover = (uint32_t)m;
    if (leftover < (uint32_t)rng_excl) {
        uint32_t threshold = (uint32_t)((uint64_t)(0xFFFFFFFFu - rng) % rng_excl);
        while (leftover < threshold) {
            m = (uint64_t)pcg_next32(g) * rng_excl;
            leftover = (uint32_t)m;
        }
    }
    return (uint32_t)(m >> 32);
}

struct Ops {
    int enc[8];
    int qfc[50];
};

constexpr void fill_ops(PCG& g, int n, int* out) {
    for (int i = 0; i < n; ++i) {
        uint32_t kind = lemire32(g, 3);
        uint32_t w0 = 0, w1 = 0;
        if (kind == 3) {
            uint32_t v2 = lemire32(g, 2);
            uint32_t v3 = lemire32(g, 3);
            uint32_t a0 = v2;
            uint32_t a1 = (v3 == v2) ? 3u : v3;
            uint32_t j = lemire32(g, 1);
            if (j == 0) { uint32_t t = a0; a0 = a1; a1 = t; }
            w0 = a0; w1 = a1;
        } else {
            w0 = lemire32(g, 3);
        }
        out[i] = (int)((kind << 4) | (w0 << 2) | w1);
    }
}

constexpr Ops make_ops_ct() {
    Ops o = {};
    PCG g1 = seed_pcg(1u);
    fill_ops(g1, 8, o.enc);
    PCG g2 = seed_pcg(2u);
    fill_ops(g2, 50, o.qfc);
    return o;
}

}  // namespace crng

constexpr crng::Ops kOps = crng::make_ops_ct();

// ---------------------------------------------------------------------------
// MFMA fragment types
// ---------------------------------------------------------------------------
typedef _Float16 half8 __attribute__((ext_vector_type(8)));
typedef float float4v __attribute__((ext_vector_type(4)));

#define XS_STRIDE 24
#define XS_PLANE  (34 * XS_STRIDE)
#define XS_TOT    (2 * XS_PLANE)
#define H1F_ROW   (18 * 8)   // halves per row

// ---------------------------------------------------------------------------
// Compile-time gate on a register-resident 16-dim complex state.
// Wire w <-> bit (3-w). All masks template constants -> straight-line FMA.
// ---------------------------------------------------------------------------
template<int KIND, int W0, int W1>
__device__ __forceinline__ void gate_ct(float (&ur)[16], float (&ui)[16],
                                        float ch, float sh)
{
    constexpr bool CTRL = (KIND == 3 || KIND == 6);
    constexpr int STT = CTRL ? (8 >> W1) : (8 >> W0);
    constexpr int STC = CTRL ? (8 >> W0) : 0;
#pragma unroll
    for (int k0 = 0; k0 < 16; ++k0) {
        if (k0 & STT) continue;
        if (STC != 0 && !(k0 & STC)) continue;
        const int k1 = k0 | STT;
        float x0r = ur[k0], x0i = ui[k0], x1r = ur[k1], x1i = ui[k1];
        if constexpr (KIND == 0 || KIND == 3) {        // RX / CRX
            ur[k0] = ch * x0r + sh * x1i;  ui[k0] = ch * x0i - sh * x1r;
            ur[k1] = sh * x0i + ch * x1r;  ui[k1] = -sh * x0r + ch * x1i;
        } else if constexpr (KIND == 1) {              // RY
            ur[k0] = ch * x0r - sh * x1r;  ui[k0] = ch * x0i - sh * x1i;
            ur[k1] = sh * x0r + ch * x1r;  ui[k1] = sh * x0i + ch * x1i;
        } else if constexpr (KIND == 2) {              // RZ
            ur[k0] = ch * x0r + sh * x0i;  ui[k0] = ch * x0i - sh * x0r;
            ur[k1] = ch * x1r - sh * x1i;  ui[k1] = ch * x1i + sh * x1r;
        } else if constexpr (KIND == 4) {              // H
            constexpr float RH = 0.70710678118654752f;
            ur[k0] = RH * (x0r + x1r);  ui[k0] = RH * (x0i + x1i);
            ur[k1] = RH * (x0r - x1r);  ui[k1] = RH * (x0i - x1i);
        } else if constexpr (KIND == 5) {              // SX
            ur[k0] = 0.5f * (x0r + x1r) - 0.5f * x0i + 0.5f * x1i;
            ui[k0] = 0.5f * (x0i + x1i) + 0.5f * x0r - 0.5f * x1r;
            ur[k1] = 0.5f * (x0r + x1r) + 0.5f * x0i - 0.5f * x1i;
            ui[k1] = 0.5f * (x0i + x1i) - 0.5f * x0r + 0.5f * x1r;
        } else {                                       // CNOT
            ur[k0] = x1r; ui[k0] = x1i;
            ur[k1] = x0r; ui[k1] = x0i;
        }
    }
}

template<int I>
__device__ __forceinline__ void run_enc(float (&ur)[16], float (&ui)[16],
                                        const float* ch, const float* sh)
{
    if constexpr (I < 8) {
        constexpr int op = kOps.enc[I];
        gate_ct<(op >> 4) & 7, (op >> 2) & 3, op & 3>(ur, ui, ch[I], sh[I]);
        run_enc<I + 1>(ur, ui, ch, sh);
    }
}

template<int I>
__device__ __forceinline__ void run_qfc(float (&ur)[16], float (&ui)[16],
                                        const float* ch, const float* sh)
{
    if constexpr (I < 50) {
        constexpr int op = kOps.qfc[I];
        gate_ct<(op >> 4) & 7, (op >> 2) & 3, op & 3>(ur, ui, ch[I], sh[I]);
        run_qfc<I + 1>(ur, ui, ch, sh);
    }
}

// ---------------------------------------------------------------------------
// Kernel 1: conv1(fp32)+pool -> h1f(f16) -> conv2 MFMA -> pool/relu/mean
//           -> pm in LDS -> 16-patch encoder sim in-block -> qfeat + sstate.
// One block per image. pm never leaves LDS (was a 2MB global round trip).
// Block 0 also resets stats[8] and the grid-barrier counter for kernel 2.
// ---------------------------------------------------------------------------
__global__ __launch_bounds__(256, 4) void cnn_enc_kernel(
    const float* __restrict__ x, const float* __restrict__ w1,
    const float* __restrict__ b1, const float* __restrict__ w2,
    const float* __restrict__ b2, const float* __restrict__ encp,
    float* __restrict__ qfeat, float* __restrict__ sstate,
    float* __restrict__ stats, int* __restrict__ bar)
{
    __shared__ float xs[XS_TOT];
    __shared__ __align__(16) _Float16 h1f[18 * H1F_ROW];   // 2592 halves
    __shared__ __align__(16) _Float16 Ahalf[9 * 16 * 8];   // 1152 halves
    __shared__ float w1s[72], b1s[8], b2s[16];
    __shared__ float pm_lds[64];
    __shared__ float chsE[8], shsE[8];

    const int tid = threadIdx.x;
    const int b = blockIdx.x;
    const float* xb = x + (size_t)b * 1024;

    for (int k = tid; k < XS_TOT; k += 256) xs[k] = 0.f;
    for (int k = tid; k < 18 * H1F_ROW; k += 256) h1f[k] = (_Float16)0.f;
    for (int e = tid; e < 1152; e += 256) {
        int uv = e >> 7, m = (e >> 3) & 15, ci = e & 7;
        Ahalf[e] = (_Float16)w2[m * 72 + ci * 9 + uv];
    }
    if (tid < 72) w1s[tid] = w1[tid];
    if (tid < 8) b1s[tid] = b1[tid];
    if (tid < 16) b2s[tid] = b2[tid];
    if (tid < 8) {
        float t = encp[tid];
        chsE[tid] = cosf(0.5f * t);
        shsE[tid] = sinf(0.5f * t);
    }
    if (b == 0 && tid < 8) stats[tid] = 0.f;
    if (b == 0 && tid == 8) *bar = 0;   // reset software grid barrier
    __syncthreads();

    // fill xs interior: one float4 per thread (even/odd column split)
    {
        const int r = tid >> 3, m = tid & 7;
        float4 v = *(const float4*)(xb + (size_t)tid * 4);
        float* d0p = &xs[(r + 1) * XS_STRIDE + 2 * m];
        float* d1p = &xs[XS_PLANE + (r + 1) * XS_STRIDE + 2 * m];
        d0p[0] = v.x;   // c=4m   even, q=2m
        d1p[1] = v.y;   // c=4m+1 odd,  q=2m+1
        d0p[1] = v.z;   // c=4m+2 even, q=2m+1
        d1p[2] = v.w;   // c=4m+3 odd,  q=2m+2
    }
    __syncthreads();

    // ---- conv1 + relu + pool (fp32), write f16 [row][col][ci] packed ----
    {
        const int i = tid >> 4, j = tid & 15;
        float patch[4][4];
#pragma unroll
        for (int u = 0; u < 4; ++u) {
            int r = 2 * i + u;
            const float* ev = &xs[r * XS_STRIDE + j];
            const float* od = &xs[XS_PLANE + r * XS_STRIDE + j];
            patch[u][0] = od[0];
            patch[u][1] = ev[0];
            patch[u][2] = od[1];
            patch[u][3] = ev[1];
        }
        half8 hv;
#pragma unroll
        for (int c = 0; c < 8; ++c) {
            float m = -3.4e38f;
#pragma unroll
            for (int di = 0; di < 2; ++di)
#pragma unroll
                for (int dj = 0; dj < 2; ++dj) {
                    float acc = b1s[c];
#pragma unroll
                    for (int u = 0; u < 3; ++u)
#pragma unroll
                        for (int v = 0; v < 3; ++v)
                            acc += w1s[c * 9 + u * 3 + v] * patch[di + u][dj + v];
                    m = fmaxf(m, acc);
                }
            hv[c] = (_Float16)fmaxf(m, 0.f);
        }
        *(half8*)&h1f[(i + 1) * H1F_ROW + (j + 1) * 8] = hv;
    }
    __syncthreads();

    // ---- conv2 as MFMA implicit GEMM + pool/relu/mean -> pm_lds ----
    {
        const int w = tid >> 6;
        const int lane = tid & 63;
        const int pj = lane & 15;
        const int quad = lane >> 4;

        half8 afrag[9];
#pragma unroll
        for (int uv = 0; uv < 9; ++uv) {
            half8 a = {};
            if (quad == 0) a = *(const half8*)&Ahalf[(uv * 16 + pj) * 8];
            afrag[uv] = a;
        }

        float4v acc[4];
#pragma unroll
        for (int tl = 0; tl < 4; ++tl) {
            float4v c;
#pragma unroll
            for (int r = 0; r < 4; ++r) c[r] = b2s[4 * quad + r];
            acc[tl] = c;
        }

#pragma unroll
        for (int tl = 0; tl < 4; ++tl) {
            const int t = 4 * w + tl;
#pragma unroll
            for (int u = 0; u < 3; ++u) {
#pragma unroll
                for (int v = 0; v < 3; ++v) {
                    half8 bf = *(const half8*)&h1f[(t + u) * H1F_ROW + (pj + v) * 8];
                    acc[tl] = __builtin_amdgcn_mfma_f32_16x16x32_f16(
                        afrag[u * 3 + v], bf, acc[tl], 0, 0, 0);
                }
            }
        }

#pragma unroll
        for (int p = 0; p < 2; ++p) {
            float4v m1;
#pragma unroll
            for (int r = 0; r < 4; ++r)
                m1[r] = fmaxf(acc[2 * p][r], acc[2 * p + 1][r]);
            float s = 0.f;
#pragma unroll
            for (int r = 0; r < 4; ++r) {
                float o = __shfl_xor((float)m1[r], 1, 64);
                float mv = fmaxf(fmaxf(m1[r], o), 0.f);
                s += mv;
            }
            s += __shfl_xor(s, 16, 64);
            s += __shfl_xor(s, 32, 64);
            if (quad == 0 && !(pj & 1)) {
                const int i2 = 2 * w + p, j2 = pj >> 1;
                pm_lds[i2 * 8 + j2] = s * (1.f / 16.f);
            }
        }
    }
    __syncthreads();

    // ---- encoder sim: 16 patch threads (wave 0), tail overlapped by
    //      other resident blocks. Patch 15's state spilled for QFC. ----
    if (tid < 16) {
        const int p = tid, pr = p >> 2, pc = p & 3;
        float d0 = pm_lds[(2 * pr) * 8 + 2 * pc];
        float d1 = pm_lds[(2 * pr) * 8 + 2 * pc + 1];
        float d2 = pm_lds[(2 * pr + 1) * 8 + 2 * pc];
        float d3 = pm_lds[(2 * pr + 1) * 8 + 2 * pc + 1];
        float f0c = cosf(0.5f * d0), f0s = sinf(0.5f * d0);
        float f1c = cosf(0.5f * d1), f1s = sinf(0.5f * d1);
        float f2c = cosf(0.5f * d2), f2s = sinf(0.5f * d2);
        float f3c = cosf(0.5f * d3), f3s = sinf(0.5f * d3);

        float ur[16], ui[16];
#pragma unroll
        for (int k = 0; k < 16; ++k) {
            float v = ((k & 8) ? f0s : f0c);
            v *= ((k & 4) ? f1s : f1c);
            v *= ((k & 2) ? f2s : f2c);
            v *= ((k & 1) ? f3s : f3c);
            ur[k] = v;
            ui[k] = 0.f;
        }
        run_enc<0>(ur, ui, chsE, shsE);

        float qv[4] = {0.f, 0.f, 0.f, 0.f};
#pragma unroll
        for (int k = 0; k < 16; ++k) {
            float pk = ur[k] * ur[k] + ui[k] * ui[k];
            qv[0] += (k & 8) ? -pk : pk;
            qv[1] += (k & 4) ? -pk : pk;
            qv[2] += (k & 2) ? -pk : pk;
            qv[3] += (k & 1) ? -pk : pk;
        }
        *(float4*)(qfeat + (size_t)b * 64 + p * 4) =
            make_float4(qv[0], qv[1], qv[2], qv[3]);

        if (p == 15) {
            float4* sp = (float4*)(sstate + (size_t)b * 32);
#pragma unroll
            for (int i = 0; i < 4; ++i)
                sp[i] = make_float4(ur[4 * i], ur[4 * i + 1], ur[4 * i + 2], ur[4 * i + 3]);
#pragma unroll
            for (int i = 0; i < 4; ++i)
                sp[4 + i] = make_float4(ui[4 * i], ui[4 * i + 1], ui[4 * i + 2], ui[4 * i + 3]);
        }
    }
}

// ---------------------------------------------------------------------------
// Kernel 2: QFC (one sample per lane, dense 64-lane waves) -> BN batch stats
// (block reduce + device atomics) -> SOFTWARE grid barrier (16 co-resident
// blocks on 256 CUs; counter reset by kernel 1) -> BN apply + FC(68->10) +
// log_softmax. Regular launch — no cooperative-launch graph-capture hazard.
// ---------------------------------------------------------------------------
__global__ __launch_bounds__(256) void tail_kernel(
    const float* __restrict__ sstate, const float* __restrict__ qfeat,
    const float* __restrict__ qfcr, const float* __restrict__ qfcp,
    const float* __restrict__ gam, const float* __restrict__ bet,
    const float* __restrict__ fcw, const float* __restrict__ fcb,
    float* __restrict__ stats, int* __restrict__ bar,
    float* __restrict__ out, int Bv, int NBlk)
{
    __shared__ float chs[54], shs[54];
    __shared__ float Wf[680];
    __shared__ float bfs[10], st8[8], ga[4], be[4];
    __shared__ float rstat[32];

    const int tid = threadIdx.x;
    if (tid < 54) {
        float t = (tid < 50) ? qfcr[tid] : qfcp[tid - 50];
        chs[tid] = cosf(0.5f * t);
        shs[tid] = sinf(0.5f * t);
    }
    for (int k = tid; k < 680; k += 256) Wf[k] = fcw[k];
    if (tid < 10) bfs[tid] = fcb[tid];
    if (tid < 4) { ga[tid] = gam[tid]; be[tid] = bet[tid]; }
    __syncthreads();

    const int b = blockIdx.x * 256 + tid;
    float qq[4] = {0.f, 0.f, 0.f, 0.f};

    if (b < Bv) {
        float ur[16], ui[16];
        const float4* sp = (const float4*)(sstate + (size_t)b * 32);
#pragma unroll
        for (int i = 0; i < 4; ++i) {
            float4 v = sp[i];
            ur[4 * i] = v.x; ur[4 * i + 1] = v.y; ur[4 * i + 2] = v.z; ur[4 * i + 3] = v.w;
        }
#pragma unroll
        for (int i = 0; i < 4; ++i) {
            float4 v = sp[4 + i];
            ui[4 * i] = v.x; ui[4 * i + 1] = v.y; ui[4 * i + 2] = v.z; ui[4 * i + 3] = v.w;
        }

        run_qfc<0>(ur, ui, chs, shs);
        gate_ct<0, 0, 0>(ur, ui, chs[50], shs[50]);  // RX wire0
        gate_ct<1, 1, 0>(ur, ui, chs[51], shs[51]);  // RY wire1
        gate_ct<2, 3, 0>(ur, ui, chs[52], shs[52]);  // RZ wire3
        gate_ct<3, 0, 2>(ur, ui, chs[53], shs[53]);  // CRX ctrl0 tgt2
        gate_ct<4, 3, 0>(ur, ui, 0.f, 0.f);          // H wire3
        gate_ct<5, 2, 0>(ur, ui, 0.f, 0.f);          // SX wire2
        gate_ct<6, 3, 0>(ur, ui, 0.f, 0.f);          // CNOT ctrl3 tgt0

#pragma unroll
        for (int k = 0; k < 16; ++k) {
            float pk = ur[k] * ur[k] + ui[k] * ui[k];
            qq[0] += (k & 8) ? -pk : pk;
            qq[1] += (k & 4) ? -pk : pk;
            qq[2] += (k & 2) ? -pk : pk;
            qq[3] += (k & 1) ? -pk : pk;
        }
    }

    // ---- batch stats: wave shuffle reduce -> LDS -> 8 atomics/block ----
    {
        const int lane = tid & 63, wv = tid >> 6;
#pragma unroll
        for (int q = 0; q < 8; ++q) {
            float v = (q < 4) ? qq[q] : qq[q - 4] * qq[q - 4];
            v += __shfl_xor(v, 1, 64);
            v += __shfl_xor(v, 2, 64);
            v += __shfl_xor(v, 4, 64);
            v += __shfl_xor(v, 8, 64);
            v += __shfl_xor(v, 16, 64);
            v += __shfl_xor(v, 32, 64);
            if (lane == 0) rstat[q * 4 + wv] = v;
        }
        __syncthreads();
        if (tid < 8)
            atomicAdd(&stats[tid], rstat[tid * 4] + rstat[tid * 4 + 1] +
                                   rstat[tid * 4 + 2] + rstat[tid * 4 + 3]);
    }

    // ---- software grid barrier (all NBlk blocks co-resident) ----
    __syncthreads();
    if (tid == 0) {
        __threadfence();                 // flush this block's atomics to L2
        atomicAdd(bar, 1);
        while (atomicAdd(bar, 0) < NBlk) // device-scope RMW = coherent read
            __builtin_amdgcn_s_sleep(8);
    }
    __syncthreads();

    // coherent read of stats (atomic RMW forces L2)
    if (tid < 8) st8[tid] = atomicAdd(&stats[tid], 0.f);
    __syncthreads();

    if (b >= Bv) return;

    const float invB = 1.f / (float)Bv;

    float logit[10];
#pragma unroll
    for (int k = 0; k < 10; ++k) logit[k] = bfs[k];

    const float* qf = qfeat + (size_t)b * 64;
#pragma unroll
    for (int j4 = 0; j4 < 16; ++j4) {
        float4 v = *(const float4*)(qf + 4 * j4);
#pragma unroll
        for (int k = 0; k < 10; ++k) {
            const float* wr = &Wf[k * 68 + 4 * j4];
            logit[k] += v.x * wr[0] + v.y * wr[1] + v.z * wr[2] + v.w * wr[3];
        }
    }
#pragma unroll
    for (int w = 0; w < 4; ++w) {
        float mu = st8[w] * invB;
        float var = st8[4 + w] * invB - mu * mu;
        float v = (qq[w] - mu) / sqrtf(var + 1e-5f) * ga[w] + be[w];
#pragma unroll
        for (int k = 0; k < 10; ++k) logit[k] += v * Wf[k * 68 + 64 + w];
    }

    float m = logit[0];
#pragma unroll
    for (int k = 1; k < 10; ++k) m = fmaxf(m, logit[k]);
    float sum = 0.f;
#pragma unroll
    for (int k = 0; k < 10; ++k) sum += expf(logit[k] - m);
    float lse = logf(sum);
#pragma unroll
    for (int k = 0; k < 10; ++k) out[(size_t)b * 10 + k] = logit[k] - m - lse;
}

// ---------------------------------------------------------------------------
extern "C" void kernel_launch(void* const* d_in, const int* in_sizes, int n_in,
                              void* d_out, int out_size, void* d_ws, size_t ws_size,
                              hipStream_t stream)
{
    const float* x    = (const float*)d_in[0];
    const float* w1   = (const float*)d_in[1];
    const float* b1   = (const float*)d_in[2];
    const float* w2   = (const float*)d_in[3];
    const float* b2   = (const float*)d_in[4];
    const float* encp = (const float*)d_in[5];
    const float* qfcr = (const float*)d_in[6];
    const float* qfcp = (const float*)d_in[7];
    const float* gam  = (const float*)d_in[8];
    const float* bet  = (const float*)d_in[9];
    const float* fcw  = (const float*)d_in[10];
    const float* fcb  = (const float*)d_in[11];
    float* out = (float*)d_out;

    const int Bv = in_sizes[0] / 1024;  // 4096

    float* qfeat  = (float*)d_ws;                   // Bv*64
    float* sstate = qfeat + (size_t)Bv * 64;        // Bv*32
    float* stats  = sstate + (size_t)Bv * 32;       // 8
    int*   bar    = (int*)(stats + 8);              // 1

    cnn_enc_kernel<<<Bv, 256, 0, stream>>>(x, w1, b1, w2, b2, encp,
                                           qfeat, sstate, stats, bar);

    const int nblk = (Bv + 255) / 256;
    tail_kernel<<<nblk, 256, 0, stream>>>(sstate, qfeat, qfcr, qfcp, gam, bet,
                                          fcw, fcb, stats, bar, out, Bv, nblk);
}

// Round 4
// 129.001 us; speedup vs baseline: 1.0884x; 1.0048x over previous
//
#include <hip/hip_runtime.h>
#include <cstdint>

// ---------------------------------------------------------------------------
// COMPILE-TIME op list: constexpr replica of numpy's RNG stream.
// op = (kind<<4) | (w0<<2) | w1
// kinds: 0 RX, 1 RY, 2 RZ, 3 CRX(ctrl=w0,tgt=w1), 4 H, 5 SX, 6 CNOT(ctrl=w0,tgt=w1)
// ---------------------------------------------------------------------------
namespace crng {

typedef unsigned __int128 u128;

struct PCG {
    u128 state, inc;
    bool has32;
    uint32_t buf32;
};

constexpr u128 PCG_MULT = (((u128)2549297995355413924ULL) << 64) | (u128)4865540595714422341ULL;

constexpr uint64_t pcg_next64(PCG& g) {
    g.state = g.state * PCG_MULT + g.inc;
    uint64_t hi = (uint64_t)(g.state >> 64), lo = (uint64_t)g.state;
    unsigned rot = (unsigned)(g.state >> 122) & 63u;
    uint64_t v = hi ^ lo;
    return (v >> rot) | (v << ((64u - rot) & 63u));
}

constexpr uint32_t pcg_next32(PCG& g) {
    if (g.has32) { g.has32 = false; return g.buf32; }
    uint64_t n = pcg_next64(g);
    g.has32 = true;
    g.buf32 = (uint32_t)(n >> 32);
    return (uint32_t)n;
}

constexpr uint32_t hashmix(uint32_t& hc, uint32_t v) {
    v ^= hc; hc *= 0x931e8875u; v *= hc; v ^= v >> 16; return v;
}
constexpr uint32_t mixf(uint32_t x, uint32_t y) {
    uint32_t r = 0xca01f9ddu * x - 0x4973f715u * y;
    r ^= r >> 16;
    return r;
}

constexpr PCG seed_pcg(uint32_t entropy) {
    uint32_t pool[4] = {0, 0, 0, 0};
    uint32_t hc = 0x43b0d7e5u;
    pool[0] = hashmix(hc, entropy);
    for (int i = 1; i < 4; ++i) pool[i] = hashmix(hc, 0u);
    for (int s = 0; s < 4; ++s)
        for (int d = 0; d < 4; ++d)
            if (s != d) pool[d] = mixf(pool[d], hashmix(hc, pool[s]));

    uint32_t hb = 0x8b51f9ddu;
    uint32_t w[8] = {0, 0, 0, 0, 0, 0, 0, 0};
    for (int i = 0; i < 8; ++i) {
        uint32_t dv = pool[i & 3];
        dv ^= hb; hb *= 0x58f38dedu; dv *= hb; dv ^= dv >> 16;
        w[i] = dv;
    }
    uint64_t w64[4] = {0, 0, 0, 0};
    for (int i = 0; i < 4; ++i)
        w64[i] = (uint64_t)w[2 * i] | ((uint64_t)w[2 * i + 1] << 32);

    u128 initstate = (((u128)w64[0]) << 64) | (u128)w64[1];
    u128 initseq   = (((u128)w64[2]) << 64) | (u128)w64[3];
    PCG g = {};
    g.state = 0;
    g.inc = (initseq << 1) | (u128)1;
    g.state = g.state * PCG_MULT + g.inc;
    g.state += initstate;
    g.state = g.state * PCG_MULT + g.inc;
    g.has32 = false;
    g.buf32 = 0;
    return g;
}

constexpr uint32_t lemire32(PCG& g, uint32_t rng) {
    uint64_t rng_excl = (uint64_t)rng + 1;
    uint64_t m = (uint64_t)pcg_next32(g) * rng_excl;
    uint32_t leftover = (uint32_t)m;
    if (leftover < (uint32_t)rng_excl) {
        uint32_t threshold = (uint32_t)((uint64_t)(0xFFFFFFFFu - rng) % rng_excl);
        while (leftover < threshold) {
            m = (uint64_t)pcg_next32(g) * rng_excl;
            leftover = (uint32_t)m;
        }
    }
    return (uint32_t)(m >> 32);
}

struct Ops {
    int enc[8];
    int qfc[50];
};

constexpr void fill_ops(PCG& g, int n, int* out) {
    for (int i = 0; i < n; ++i) {
        uint32_t kind = lemire32(g, 3);
        uint32_t w0 = 0, w1 = 0;
        if (kind == 3) {
            uint32_t v2 = lemire32(g, 2);
            uint32_t v3 = lemire32(g, 3);
            uint32_t a0 = v2;
            uint32_t a1 = (v3 == v2) ? 3u : v3;
            uint32_t j = lemire32(g, 1);
            if (j == 0) { uint32_t t = a0; a0 = a1; a1 = t; }
            w0 = a0; w1 = a1;
        } else {
            w0 = lemire32(g, 3);
        }
        out[i] = (int)((kind << 4) | (w0 << 2) | w1);
    }
}

constexpr Ops make_ops_ct() {
    Ops o = {};
    PCG g1 = seed_pcg(1u);
    fill_ops(g1, 8, o.enc);
    PCG g2 = seed_pcg(2u);
    fill_ops(g2, 50, o.qfc);
    return o;
}

}  // namespace crng

constexpr crng::Ops kOps = crng::make_ops_ct();

// ---------------------------------------------------------------------------
// MFMA fragment types
// ---------------------------------------------------------------------------
typedef _Float16 half8 __attribute__((ext_vector_type(8)));
typedef float float4v __attribute__((ext_vector_type(4)));

#define XS_STRIDE 24
#define XS_PLANE  (34 * XS_STRIDE)
#define XS_TOT    (2 * XS_PLANE)
#define H1F_ROW   (18 * 8)   // halves per row

// ---------------------------------------------------------------------------
// Compile-time gate on a register-resident 16-dim complex state.
// Wire w <-> bit (3-w). All masks template constants -> straight-line FMA.
// ---------------------------------------------------------------------------
template<int KIND, int W0, int W1>
__device__ __forceinline__ void gate_ct(float (&ur)[16], float (&ui)[16],
                                        float ch, float sh)
{
    constexpr bool CTRL = (KIND == 3 || KIND == 6);
    constexpr int STT = CTRL ? (8 >> W1) : (8 >> W0);
    constexpr int STC = CTRL ? (8 >> W0) : 0;
#pragma unroll
    for (int k0 = 0; k0 < 16; ++k0) {
        if (k0 & STT) continue;
        if (STC != 0 && !(k0 & STC)) continue;
        const int k1 = k0 | STT;
        float x0r = ur[k0], x0i = ui[k0], x1r = ur[k1], x1i = ui[k1];
        if constexpr (KIND == 0 || KIND == 3) {        // RX / CRX
            ur[k0] = ch * x0r + sh * x1i;  ui[k0] = ch * x0i - sh * x1r;
            ur[k1] = sh * x0i + ch * x1r;  ui[k1] = -sh * x0r + ch * x1i;
        } else if constexpr (KIND == 1) {              // RY
            ur[k0] = ch * x0r - sh * x1r;  ui[k0] = ch * x0i - sh * x1i;
            ur[k1] = sh * x0r + ch * x1r;  ui[k1] = sh * x0i + ch * x1i;
        } else if constexpr (KIND == 2) {              // RZ
            ur[k0] = ch * x0r + sh * x0i;  ui[k0] = ch * x0i - sh * x0r;
            ur[k1] = ch * x1r - sh * x1i;  ui[k1] = ch * x1i + sh * x1r;
        } else if constexpr (KIND == 4) {              // H
            constexpr float RH = 0.70710678118654752f;
            ur[k0] = RH * (x0r + x1r);  ui[k0] = RH * (x0i + x1i);
            ur[k1] = RH * (x0r - x1r);  ui[k1] = RH * (x0i - x1i);
        } else if constexpr (KIND == 5) {              // SX
            ur[k0] = 0.5f * (x0r + x1r) - 0.5f * x0i + 0.5f * x1i;
            ui[k0] = 0.5f * (x0i + x1i) + 0.5f * x0r - 0.5f * x1r;
            ur[k1] = 0.5f * (x0r + x1r) + 0.5f * x0i - 0.5f * x1i;
            ui[k1] = 0.5f * (x0i + x1i) - 0.5f * x0r + 0.5f * x1r;
        } else {                                       // CNOT
            ur[k0] = x1r; ui[k0] = x1i;
            ur[k1] = x0r; ui[k1] = x0i;
        }
    }
}

template<int I>
__device__ __forceinline__ void run_enc(float (&ur)[16], float (&ui)[16],
                                        const float* ch, const float* sh)
{
    if constexpr (I < 8) {
        constexpr int op = kOps.enc[I];
        gate_ct<(op >> 4) & 7, (op >> 2) & 3, op & 3>(ur, ui, ch[I], sh[I]);
        run_enc<I + 1>(ur, ui, ch, sh);
    }
}

template<int I>
__device__ __forceinline__ void run_qfc(float (&ur)[16], float (&ui)[16],
                                        const float* ch, const float* sh)
{
    if constexpr (I < 50) {
        constexpr int op = kOps.qfc[I];
        gate_ct<(op >> 4) & 7, (op >> 2) & 3, op & 3>(ur, ui, ch[I], sh[I]);
        run_qfc<I + 1>(ur, ui, ch, sh);
    }
}

// ---------------------------------------------------------------------------
// Kernel 1: 4 images per block (grid Bv/4 = 1024 = exact 4-block/CU
// residency). Staging (halo zero, Ahalf, weights, enc cos/sin) amortized 4x.
// Per image: conv1(fp32)+pool -> h1f(f16) -> conv2 MFMA -> pool/relu/mean
// -> pm_lds[img]. Then ONE DENSE WAVE (64 lanes = 4 img x 16 patches) runs
// the encoder sim. Block 0 resets the grid-barrier counter for kernel 2.
// ---------------------------------------------------------------------------
__global__ __launch_bounds__(256, 4) void cnn_enc_kernel(
    const float* __restrict__ x, const float* __restrict__ w1,
    const float* __restrict__ b1, const float* __restrict__ w2,
    const float* __restrict__ b2, const float* __restrict__ encp,
    float* __restrict__ qfeat, float* __restrict__ sstate,
    int* __restrict__ bar, int Bv)
{
    __shared__ float xs[XS_TOT];
    __shared__ __align__(16) _Float16 h1f[18 * H1F_ROW];   // 2592 halves
    __shared__ __align__(16) _Float16 Ahalf[9 * 16 * 8];   // 1152 halves
    __shared__ float w1s[72], b1s[8], b2s[16];
    __shared__ float pm_lds[4][64];
    __shared__ float chsE[8], shsE[8];

    const int tid = threadIdx.x;
    const int b4 = blockIdx.x * 4;

    // one-time staging: zero halos, build Ahalf, load weights + enc angles
    for (int k = tid; k < XS_TOT; k += 256) xs[k] = 0.f;
    for (int k = tid; k < 18 * H1F_ROW; k += 256) h1f[k] = (_Float16)0.f;
    for (int e = tid; e < 1152; e += 256) {
        int uv = e >> 7, m = (e >> 3) & 15, ci = e & 7;
        Ahalf[e] = (_Float16)w2[m * 72 + ci * 9 + uv];
    }
    if (tid < 72) w1s[tid] = w1[tid];
    if (tid < 8) b1s[tid] = b1[tid];
    if (tid < 16) b2s[tid] = b2[tid];
    if (tid < 8) {
        float t = encp[tid];
        chsE[tid] = cosf(0.5f * t);
        shsE[tid] = sinf(0.5f * t);
    }
    if (blockIdx.x == 0 && tid == 8)
        atomicExch(bar, 0);   // device-scope reset of software grid barrier
    __syncthreads();

    for (int img = 0; img < 4; ++img) {
        const int bimg = b4 + img;
        const float* xb = x + (size_t)((bimg < Bv) ? bimg : (Bv - 1)) * 1024;

        // fill xs interior: one float4 per thread (even/odd column split)
        {
            const int r = tid >> 3, m = tid & 7;
            float4 v = *(const float4*)(xb + (size_t)tid * 4);
            float* d0p = &xs[(r + 1) * XS_STRIDE + 2 * m];
            float* d1p = &xs[XS_PLANE + (r + 1) * XS_STRIDE + 2 * m];
            d0p[0] = v.x;   // c=4m   even, q=2m
            d1p[1] = v.y;   // c=4m+1 odd,  q=2m+1
            d0p[1] = v.z;   // c=4m+2 even, q=2m+1
            d1p[2] = v.w;   // c=4m+3 odd,  q=2m+2
        }
        __syncthreads();

        // ---- conv1 + relu + pool (fp32), write f16 [row][col][ci] ----
        {
            const int i = tid >> 4, j = tid & 15;
            float patch[4][4];
#pragma unroll
            for (int u = 0; u < 4; ++u) {
                int r = 2 * i + u;
                const float* ev = &xs[r * XS_STRIDE + j];
                const float* od = &xs[XS_PLANE + r * XS_STRIDE + j];
                patch[u][0] = od[0];
                patch[u][1] = ev[0];
                patch[u][2] = od[1];
                patch[u][3] = ev[1];
            }
            half8 hv;
#pragma unroll
            for (int c = 0; c < 8; ++c) {
                float m = -3.4e38f;
#pragma unroll
                for (int di = 0; di < 2; ++di)
#pragma unroll
                    for (int dj = 0; dj < 2; ++dj) {
                        float acc = b1s[c];
#pragma unroll
                        for (int u = 0; u < 3; ++u)
#pragma unroll
                            for (int v = 0; v < 3; ++v)
                                acc += w1s[c * 9 + u * 3 + v] * patch[di + u][dj + v];
                        m = fmaxf(m, acc);
                    }
                hv[c] = (_Float16)fmaxf(m, 0.f);
            }
            *(half8*)&h1f[(i + 1) * H1F_ROW + (j + 1) * 8] = hv;
        }
        __syncthreads();

        // ---- conv2 as MFMA implicit GEMM + pool/relu/mean -> pm_lds ----
        {
            const int w = tid >> 6;
            const int lane = tid & 63;
            const int pj = lane & 15;
            const int quad = lane >> 4;

            half8 afrag[9];
#pragma unroll
            for (int uv = 0; uv < 9; ++uv) {
                half8 a = {};
                if (quad == 0) a = *(const half8*)&Ahalf[(uv * 16 + pj) * 8];
                afrag[uv] = a;
            }

            float4v acc[4];
#pragma unroll
            for (int tl = 0; tl < 4; ++tl) {
                float4v c;
#pragma unroll
                for (int r = 0; r < 4; ++r) c[r] = b2s[4 * quad + r];
                acc[tl] = c;
            }

#pragma unroll
            for (int tl = 0; tl < 4; ++tl) {
                const int t = 4 * w + tl;
#pragma unroll
                for (int u = 0; u < 3; ++u) {
#pragma unroll
                    for (int v = 0; v < 3; ++v) {
                        half8 bf = *(const half8*)&h1f[(t + u) * H1F_ROW + (pj + v) * 8];
                        acc[tl] = __builtin_amdgcn_mfma_f32_16x16x32_f16(
                            afrag[u * 3 + v], bf, acc[tl], 0, 0, 0);
                    }
                }
            }

#pragma unroll
            for (int p = 0; p < 2; ++p) {
                float4v m1;
#pragma unroll
                for (int r = 0; r < 4; ++r)
                    m1[r] = fmaxf(acc[2 * p][r], acc[2 * p + 1][r]);
                float s = 0.f;
#pragma unroll
                for (int r = 0; r < 4; ++r) {
                    float o = __shfl_xor((float)m1[r], 1, 64);
                    float mv = fmaxf(fmaxf(m1[r], o), 0.f);
                    s += mv;
                }
                s += __shfl_xor(s, 16, 64);
                s += __shfl_xor(s, 32, 64);
                if (quad == 0 && !(pj & 1)) {
                    const int i2 = 2 * w + p, j2 = pj >> 1;
                    pm_lds[img][i2 * 8 + j2] = s * (1.f / 16.f);
                }
            }
        }
        __syncthreads();   // pm_lds[img] ready; also guards xs/h1f overwrite
    }

    // ---- encoder sim: ONE DENSE WAVE. lane = img*16 + patch. ----
    if (tid < 64) {
        const int img = tid >> 4, p = tid & 15;
        const int bimg = b4 + img;
        if (bimg < Bv) {
            const int pr = p >> 2, pc = p & 3;
            const float* pmi = pm_lds[img];
            float d0 = pmi[(2 * pr) * 8 + 2 * pc];
            float d1 = pmi[(2 * pr) * 8 + 2 * pc + 1];
            float d2 = pmi[(2 * pr + 1) * 8 + 2 * pc];
            float d3 = pmi[(2 * pr + 1) * 8 + 2 * pc + 1];
            float f0c = cosf(0.5f * d0), f0s = sinf(0.5f * d0);
            float f1c = cosf(0.5f * d1), f1s = sinf(0.5f * d1);
            float f2c = cosf(0.5f * d2), f2s = sinf(0.5f * d2);
            float f3c = cosf(0.5f * d3), f3s = sinf(0.5f * d3);

            float ur[16], ui[16];
#pragma unroll
            for (int k = 0; k < 16; ++k) {
                float v = ((k & 8) ? f0s : f0c);
                v *= ((k & 4) ? f1s : f1c);
                v *= ((k & 2) ? f2s : f2c);
                v *= ((k & 1) ? f3s : f3c);
                ur[k] = v;
                ui[k] = 0.f;
            }
            run_enc<0>(ur, ui, chsE, shsE);

            float qv[4] = {0.f, 0.f, 0.f, 0.f};
#pragma unroll
            for (int k = 0; k < 16; ++k) {
                float pk = ur[k] * ur[k] + ui[k] * ui[k];
                qv[0] += (k & 8) ? -pk : pk;
                qv[1] += (k & 4) ? -pk : pk;
                qv[2] += (k & 2) ? -pk : pk;
                qv[3] += (k & 1) ? -pk : pk;
            }
            *(float4*)(qfeat + (size_t)bimg * 64 + p * 4) =
                make_float4(qv[0], qv[1], qv[2], qv[3]);

            if (p == 15) {
                float4* sp = (float4*)(sstate + (size_t)bimg * 32);
#pragma unroll
                for (int i = 0; i < 4; ++i)
                    sp[i] = make_float4(ur[4 * i], ur[4 * i + 1], ur[4 * i + 2], ur[4 * i + 3]);
#pragma unroll
                for (int i = 0; i < 4; ++i)
                    sp[4 + i] = make_float4(ui[4 * i], ui[4 * i + 1], ui[4 * i + 2], ui[4 * i + 3]);
            }
        }
    }
}

// ---------------------------------------------------------------------------
// Kernel 2: QFC (one sample per lane) -> BN batch stats via DETERMINISTIC
// per-block slots (atomicExch into pstat[block][8]; no order-dependent float
// accumulation) -> software grid barrier (16 co-resident blocks) -> every
// block sums the 16 partials in FIXED index order (bitwise identical across
// runs and blocks) -> BN apply + FC(68->10) + log_softmax.
// ---------------------------------------------------------------------------
__global__ __launch_bounds__(256) void tail_kernel(
    const float* __restrict__ sstate, const float* __restrict__ qfeat,
    const float* __restrict__ qfcr, const float* __restrict__ qfcp,
    const float* __restrict__ gam, const float* __restrict__ bet,
    const float* __restrict__ fcw, const float* __restrict__ fcb,
    float* __restrict__ pstat, int* __restrict__ bar,
    float* __restrict__ out, int Bv, int NBlk)
{
    __shared__ float chs[54], shs[54];
    __shared__ float Wf[680];
    __shared__ float bfs[10], st8[8], ga[4], be[4];
    __shared__ float rstat[32];
    __shared__ float allp[128];   // NBlk(16) x 8 partials

    const int tid = threadIdx.x;
    if (tid < 54) {
        float t = (tid < 50) ? qfcr[tid] : qfcp[tid - 50];
        chs[tid] = cosf(0.5f * t);
        shs[tid] = sinf(0.5f * t);
    }
    for (int k = tid; k < 680; k += 256) Wf[k] = fcw[k];
    if (tid < 10) bfs[tid] = fcb[tid];
    if (tid < 4) { ga[tid] = gam[tid]; be[tid] = bet[tid]; }
    __syncthreads();

    const int b = blockIdx.x * 256 + tid;
    float qq[4] = {0.f, 0.f, 0.f, 0.f};

    if (b < Bv) {
        float ur[16], ui[16];
        const float4* sp = (const float4*)(sstate + (size_t)b * 32);
#pragma unroll
        for (int i = 0; i < 4; ++i) {
            float4 v = sp[i];
            ur[4 * i] = v.x; ur[4 * i + 1] = v.y; ur[4 * i + 2] = v.z; ur[4 * i + 3] = v.w;
        }
#pragma unroll
        for (int i = 0; i < 4; ++i) {
            float4 v = sp[4 + i];
            ui[4 * i] = v.x; ui[4 * i + 1] = v.y; ui[4 * i + 2] = v.z; ui[4 * i + 3] = v.w;
        }

        run_qfc<0>(ur, ui, chs, shs);
        gate_ct<0, 0, 0>(ur, ui, chs[50], shs[50]);  // RX wire0
        gate_ct<1, 1, 0>(ur, ui, chs[51], shs[51]);  // RY wire1
        gate_ct<2, 3, 0>(ur, ui, chs[52], shs[52]);  // RZ wire3
        gate_ct<3, 0, 2>(ur, ui, chs[53], shs[53]);  // CRX ctrl0 tgt2
        gate_ct<4, 3, 0>(ur, ui, 0.f, 0.f);          // H wire3
        gate_ct<5, 2, 0>(ur, ui, 0.f, 0.f);          // SX wire2
        gate_ct<6, 3, 0>(ur, ui, 0.f, 0.f);          // CNOT ctrl3 tgt0

#pragma unroll
        for (int k = 0; k < 16; ++k) {
            float pk = ur[k] * ur[k] + ui[k] * ui[k];
            qq[0] += (k & 8) ? -pk : pk;
            qq[1] += (k & 4) ? -pk : pk;
            qq[2] += (k & 2) ? -pk : pk;
            qq[3] += (k & 1) ? -pk : pk;
        }
    }

    // ---- batch stats: wave shuffle reduce -> LDS -> per-block slot ----
    {
        const int lane = tid & 63, wv = tid >> 6;
#pragma unroll
        for (int q = 0; q < 8; ++q) {
            float v = (q < 4) ? qq[q] : qq[q - 4] * qq[q - 4];
            v += __shfl_xor(v, 1, 64);
            v += __shfl_xor(v, 2, 64);
            v += __shfl_xor(v, 4, 64);
            v += __shfl_xor(v, 8, 64);
            v += __shfl_xor(v, 16, 64);
            v += __shfl_xor(v, 32, 64);
            if (lane == 0) rstat[q * 4 + wv] = v;
        }
        __syncthreads();
        if (tid < 8) {
            // fixed association order -> deterministic partial
            float pv = ((rstat[tid * 4 + 0] + rstat[tid * 4 + 1]) +
                        rstat[tid * 4 + 2]) + rstat[tid * 4 + 3];
            // device-scope overwrite of this block's slot (no ordering dep)
            atomicExch(&pstat[blockIdx.x * 8 + tid], pv);
        }
    }

    // ---- software grid barrier (all NBlk blocks co-resident) ----
    __syncthreads();
    if (tid == 0) {
        __threadfence();                 // slot writes globally visible first
        atomicAdd(bar, 1);
        while (atomicAdd(bar, 0) < NBlk) // device-scope RMW = coherent read
            __builtin_amdgcn_s_sleep(8);
    }
    __syncthreads();

    // coherent parallel read of all partials, then FIXED-ORDER sum
    if (tid < 8 * NBlk)
        allp[tid] = atomicAdd(&pstat[tid], 0.f);
    __syncthreads();
    if (tid < 8) {
        float s = 0.f;
        for (int k = 0; k < NBlk; ++k) s += allp[k * 8 + tid];
        st8[tid] = s;
    }
    __syncthreads();

    if (b >= Bv) return;

    const float invB = 1.f / (float)Bv;

    float logit[10];
#pragma unroll
    for (int k = 0; k < 10; ++k) logit[k] = bfs[k];

    const float* qf = qfeat + (size_t)b * 64;
#pragma unroll
    for (int j4 = 0; j4 < 16; ++j4) {
        float4 v = *(const float4*)(qf + 4 * j4);
#pragma unroll
        for (int k = 0; k < 10; ++k) {
            const float* wr = &Wf[k * 68 + 4 * j4];
            logit[k] += v.x * wr[0] + v.y * wr[1] + v.z * wr[2] + v.w * wr[3];
        }
    }
#pragma unroll
    for (int w = 0; w < 4; ++w) {
        float mu = st8[w] * invB;
        float var = st8[4 + w] * invB - mu * mu;
        float v = (qq[w] - mu) / sqrtf(var + 1e-5f) * ga[w] + be[w];
#pragma unroll
        for (int k = 0; k < 10; ++k) logit[k] += v * Wf[k * 68 + 64 + w];
    }

    float m = logit[0];
#pragma unroll
    for (int k = 1; k < 10; ++k) m = fmaxf(m, logit[k]);
    float sum = 0.f;
#pragma unroll
    for (int k = 0; k < 10; ++k) sum += expf(logit[k] - m);
    float lse = logf(sum);
#pragma unroll
    for (int k = 0; k < 10; ++k) out[(size_t)b * 10 + k] = logit[k] - m - lse;
}

// ---------------------------------------------------------------------------
extern "C" void kernel_launch(void* const* d_in, const int* in_sizes, int n_in,
                              void* d_out, int out_size, void* d_ws, size_t ws_size,
                              hipStream_t stream)
{
    const float* x    = (const float*)d_in[0];
    const float* w1   = (const float*)d_in[1];
    const float* b1   = (const float*)d_in[2];
    const float* w2   = (const float*)d_in[3];
    const float* b2   = (const float*)d_in[4];
    const float* encp = (const float*)d_in[5];
    const float* qfcr = (const float*)d_in[6];
    const float* qfcp = (const float*)d_in[7];
    const float* gam  = (const float*)d_in[8];
    const float* bet  = (const float*)d_in[9];
    const float* fcw  = (const float*)d_in[10];
    const float* fcb  = (const float*)d_in[11];
    float* out = (float*)d_out;

    const int Bv = in_sizes[0] / 1024;  // 4096

    float* qfeat  = (float*)d_ws;                   // Bv*64
    float* sstate = qfeat + (size_t)Bv * 64;        // Bv*32
    float* pstat  = sstate + (size_t)Bv * 32;       // 16*8 per-block partials
    int*   bar    = (int*)(pstat + 128);            // 1

    const int nblk1 = (Bv + 3) / 4;                 // 1024 = 4 blocks/CU x 256 CU
    cnn_enc_kernel<<<nblk1, 256, 0, stream>>>(x, w1, b1, w2, b2, encp,
                                              qfeat, sstate, bar, Bv);

    const int nblk2 = (Bv + 255) / 256;             // 16
    tail_kernel<<<nblk2, 256, 0, stream>>>(sstate, qfeat, qfcr, qfcp, gam, bet,
                                           fcw, fcb, pstat, bar, out, Bv, nblk2);
}